// Round 1
// 2971.882 us; speedup vs baseline: 1.6580x; 1.6580x over previous
//
#include <hip/hip_runtime.h>
#include <math.h>

// DecoderLSTM greedy decode, MI355X. V=32000 H=1024 T=32 B=64.
// Logits GEMM: bf16 MFMA (16x16x32) with 3-term split (hi*hi + hi*lo + lo*hi),
// fp32 accumulate -> per-logit error ~1e-5, no feedback into recurrence.
// Gates GEMM stays fp32 (recurrence amplifies its error ~10^3x over 32 steps).
//
// R1 change: argmax/softmax folded into logits epilogue as per-block partials
// (register-resident values, all 250 blocks), plus a 64-block finalize kernel.
// hsplit fused into lstm. 5 -> 4 dispatches/step; removes the 64-block
// two-pass 32000-element scan that was ~25% CU-occupancy serial work.
//
// ws layout:
//   floats: x[1024][64]@0  h[1024][64]@65536  c[1024][64]@131072
//           part[8][4096][64]@196608  (ends 2293760)
//           pmax[64][256]@2293760 psum[64][256]@2310144 pidx(int)[64][256]@2326528
//   ushort (bf16), at float offset 2359296:
//           Whi[32000][1024], Wlo[32000][1024], Hhi[64][1024], Hlo[64][1024]

typedef short bf16x8 __attribute__((ext_vector_type(8)));
typedef float f32x4 __attribute__((ext_vector_type(4)));

constexpr int kH = 1024;
constexpr int kFH = 4096;
constexpr int kB = 64;
constexpr int kV = 32000;
constexpr int kT = 32;
constexpr int kSOS = 1;
constexpr int kEOS = 2;

__device__ inline unsigned short f2bf(float f) {  // RNE float->bf16
  unsigned int u = __float_as_uint(f);
  u += 0x7fffu + ((u >> 16) & 1u);
  return (unsigned short)(u >> 16);
}
__device__ inline float bf2f(unsigned short h) {
  return __uint_as_float(((unsigned int)h) << 16);
}

// ---------------------------------------------------------------- init ------
__global__ __launch_bounds__(256) void init_kernel(
    const float* __restrict__ E, const float* __restrict__ eh,
    const float* __restrict__ ec, float* __restrict__ ws) {
  int g = blockIdx.x * 256 + threadIdx.x;  // 0..65535
  int u = g >> 6, b = g & 63;
  float* x = ws;
  float* h = ws + 65536;
  float* c = ws + 131072;
  x[g] = E[(size_t)kSOS * kH + u];
  h[u * 64 + b] = eh[(size_t)b * kH + u];
  c[u * 64 + b] = ec[(size_t)b * kH + u];
}

// ------------------------------------------------------------- W split ------
// Whi = bf16(W), Wlo = bf16(W - Whi). 32000*1024 elems, 4/thread.
__global__ __launch_bounds__(256) void wsplit_kernel(
    const float* __restrict__ W, unsigned short* __restrict__ hi,
    unsigned short* __restrict__ lo) {
  size_t i = ((size_t)blockIdx.x * 256 + threadIdx.x) * 4;
  float4 w = *(const float4*)(W + i);
  unsigned short h0 = f2bf(w.x), h1 = f2bf(w.y), h2 = f2bf(w.z), h3 = f2bf(w.w);
  ushort4 hv = make_ushort4(h0, h1, h2, h3);
  ushort4 lv = make_ushort4(f2bf(w.x - bf2f(h0)), f2bf(w.y - bf2f(h1)),
                            f2bf(w.z - bf2f(h2)), f2bf(w.w - bf2f(h3)));
  *(ushort4*)(hi + i) = hv;
  *(ushort4*)(lo + i) = lv;
}

// --------------------------------------------------------------- gates ------
// part[s][r][b] += W[r][k] * z[k][b]. grid(64,8). fp32, unchanged (passed R1).
__global__ __launch_bounds__(256) void gates_kernel(
    const float* __restrict__ Wih, const float* __restrict__ Whh,
    const float* __restrict__ x, const float* __restrict__ h,
    float* __restrict__ part) {
  __shared__ __align__(16) float Wt[64 * 68];
  __shared__ __align__(16) float Zt[64 * 68];
  const int tid = threadIdx.x;
  const int s = blockIdx.y;
  const int r0 = blockIdx.x * 64;
  const int phase = s >> 2;
  const int kc0 = (s & 3) * 256;
  const float* __restrict__ W = phase ? Whh : Wih;
  const float* __restrict__ z = phase ? h : x;
  const int tb4 = tid & 15;
  const int tr4 = tid >> 4;
  float acc[4][4];
#pragma unroll
  for (int i = 0; i < 4; ++i)
#pragma unroll
    for (int j = 0; j < 4; ++j) acc[i][j] = 0.f;

  for (int kc = kc0; kc < kc0 + 256; kc += 64) {
#pragma unroll
    for (int l = 0; l < 4; ++l) {
      int f4 = tid + 256 * l;
      int row = f4 >> 4;
      int c4 = f4 & 15;
      float4 w = *(const float4*)(W + (size_t)(r0 + row) * kH + kc + c4 * 4);
      float wv[4] = {w.x, w.y, w.z, w.w};
#pragma unroll
      for (int cc = 0; cc < 4; ++cc) {
        int c = (cc + c4) & 3;
        Wt[(c4 * 4 + c) * 68 + row] = wv[c];
      }
    }
#pragma unroll
    for (int l = 0; l < 4; ++l) {
      int f4 = tid + 256 * l;
      int kk = f4 >> 4;
      int b4 = f4 & 15;
      *(float4*)(&Zt[kk * 68 + b4 * 4]) =
          *(const float4*)(z + (size_t)(kc + kk) * 64 + b4 * 4);
    }
    __syncthreads();
#pragma unroll
    for (int kk = 0; kk < 64; ++kk) {
      float4 a = *(const float4*)(&Wt[kk * 68 + tr4 * 4]);
      float4 zb = *(const float4*)(&Zt[kk * 68 + tb4 * 4]);
      float av[4] = {a.x, a.y, a.z, a.w};
      float zv[4] = {zb.x, zb.y, zb.z, zb.w};
#pragma unroll
      for (int i = 0; i < 4; ++i)
#pragma unroll
        for (int j = 0; j < 4; ++j) acc[i][j] += av[i] * zv[j];
    }
    __syncthreads();
  }
#pragma unroll
  for (int i = 0; i < 4; ++i) {
    float4 o = make_float4(acc[i][0], acc[i][1], acc[i][2], acc[i][3]);
    *(float4*)(&part[((size_t)s * kFH + r0 + tr4 * 4 + i) * 64 + tb4 * 4]) = o;
  }
}

// ------------------------------------------------- lstm (+ hsplit fused) ----
__global__ __launch_bounds__(256) void lstm_kernel(
    const float* __restrict__ part, const float* __restrict__ bih,
    const float* __restrict__ bhh, float* __restrict__ h,
    float* __restrict__ c, unsigned short* __restrict__ Hhi,
    unsigned short* __restrict__ Hlo) {
  int g = blockIdx.x * 256 + threadIdx.x;
  int b = g & 63, u = g >> 6;
  float gate[4];
#pragma unroll
  for (int ty = 0; ty < 4; ++ty) {
    int r = ty * kH + u;
    float acc = bih[r] + bhh[r];
#pragma unroll
    for (int s2 = 0; s2 < 8; ++s2)
      acc += part[((size_t)s2 * kFH + r) * 64 + b];
    gate[ty] = acc;
  }
  float gi = 1.f / (1.f + expf(-gate[0]));
  float gf = 1.f / (1.f + expf(-gate[1]));
  float gg = tanhf(gate[2]);
  float go = 1.f / (1.f + expf(-gate[3]));
  float cn = gf * c[g] + gi * gg;
  float hn = go * tanhf(cn);
  c[g] = cn;
  h[g] = hn;
  // hsplit fused: transpose+split scatter (2B stores, 256 KB total -> cheap)
  unsigned short hb = f2bf(hn);
  Hhi[(size_t)b * kH + u] = hb;
  Hlo[(size_t)b * kH + u] = f2bf(hn - bf2f(hb));
}

// ------------------------------------------------------- logits (MFMA) ------
// out[b][v] = sum_k W[v][k] h[k][b] + bout[v], 3-term bf16 split, no LDS in
// the main loop. Block 256 thr = 4 waves; wave = 32v x 64b; grid 250.
// Epilogue: per-block softmax/argmax partials from the live accumulators.
struct Frags {
  bf16x8 ah[2], al[2], bh[4], bl[4];
};

__device__ inline void load_frags(Frags& f, const unsigned short* wp0,
                                  const unsigned short* wp1,
                                  const unsigned short* lp0,
                                  const unsigned short* lp1,
                                  const unsigned short* hh,
                                  const unsigned short* hl, int ko) {
  f.ah[0] = *(const bf16x8*)(wp0 + ko);
  f.ah[1] = *(const bf16x8*)(wp1 + ko);
  f.al[0] = *(const bf16x8*)(lp0 + ko);
  f.al[1] = *(const bf16x8*)(lp1 + ko);
#pragma unroll
  for (int bt = 0; bt < 4; ++bt) {
    f.bh[bt] = *(const bf16x8*)(hh + bt * 16 * kH + ko);
    f.bl[bt] = *(const bf16x8*)(hl + bt * 16 * kH + ko);
  }
}

__device__ inline void do_mfma(const Frags& f, f32x4 acc[2][4]) {
#pragma unroll
  for (int tv = 0; tv < 2; ++tv)
#pragma unroll
    for (int bt = 0; bt < 4; ++bt) {
      acc[tv][bt] = __builtin_amdgcn_mfma_f32_16x16x32_bf16(
          f.ah[tv], f.bh[bt], acc[tv][bt], 0, 0, 0);
      acc[tv][bt] = __builtin_amdgcn_mfma_f32_16x16x32_bf16(
          f.ah[tv], f.bl[bt], acc[tv][bt], 0, 0, 0);
      acc[tv][bt] = __builtin_amdgcn_mfma_f32_16x16x32_bf16(
          f.al[tv], f.bh[bt], acc[tv][bt], 0, 0, 0);
    }
}

__global__ __launch_bounds__(256) void logits_mfma_kernel(
    const unsigned short* __restrict__ Whi, const unsigned short* __restrict__ Wlo,
    const unsigned short* __restrict__ Hhi, const unsigned short* __restrict__ Hlo,
    const float* __restrict__ bout, float* __restrict__ out,
    float* __restrict__ pmax_g, float* __restrict__ psum_g,
    int* __restrict__ pidx_g) {
  const int tid = threadIdx.x;
  const int wave = tid >> 6, lane = tid & 63;
  const int m = lane & 15, q = lane >> 4;
  const int v0 = blockIdx.x * 128 + wave * 32;
  const unsigned short* wp0 = Whi + (size_t)(v0 + m) * kH + q * 8;
  const unsigned short* wp1 = Whi + (size_t)(v0 + 16 + m) * kH + q * 8;
  const unsigned short* lp0 = Wlo + (size_t)(v0 + m) * kH + q * 8;
  const unsigned short* lp1 = Wlo + (size_t)(v0 + 16 + m) * kH + q * 8;
  const unsigned short* hh = Hhi + (size_t)m * kH + q * 8;
  const unsigned short* hl = Hlo + (size_t)m * kH + q * 8;

  f32x4 acc[2][4];
#pragma unroll
  for (int tv = 0; tv < 2; ++tv)
#pragma unroll
    for (int bt = 0; bt < 4; ++bt) acc[tv][bt] = (f32x4){0.f, 0.f, 0.f, 0.f};

  Frags f0, f1;
  load_frags(f0, wp0, wp1, lp0, lp1, hh, hl, 0);
  // 32 k-chunks, unrolled x2 with double-buffered fragments
  for (int kc = 0; kc < kH; kc += 64) {
    if (kc + 32 < kH) load_frags(f1, wp0, wp1, lp0, lp1, hh, hl, kc + 32);
    do_mfma(f0, acc);
    if (kc + 64 < kH) load_frags(f0, wp0, wp1, lp0, lp1, hh, hl, kc + 64);
    do_mfma(f1, acc);
  }

  // D layout: row(v) = q*4 + reg, col(b) = lane&15. Add bias in-place so the
  // accumulators hold the final logits for the partial reduction below.
  float4 bo0 = *(const float4*)(bout + v0 + q * 4);
  float4 bo1 = *(const float4*)(bout + v0 + 16 + q * 4);
#pragma unroll
  for (int tv = 0; tv < 2; ++tv) {
    float4 bo = tv ? bo1 : bo0;
#pragma unroll
    for (int bt = 0; bt < 4; ++bt) {
      int b = bt * 16 + m;
      f32x4 a = acc[tv][bt];
      a[0] += bo.x; a[1] += bo.y; a[2] += bo.z; a[3] += bo.w;
      acc[tv][bt] = a;
      float4 o = make_float4(a[0], a[1], a[2], a[3]);
      *(float4*)(out + (size_t)b * kV + v0 + tv * 16 + q * 4) = o;
    }
  }

  // ---- per-block softmax/argmax partials (per b: max, first-argmax, sumexp)
  __shared__ float lred[4][4][64];  // [wave][q][b]
  __shared__ int lidx[4][4][64];
  __shared__ float bbm[64];
  const int blk = blockIdx.x;
  const int vbase = blk * 128;  // block's v range: vbase .. vbase+127

#pragma unroll
  for (int bt = 0; bt < 4; ++bt) {
    float pmv = -INFINITY;
    int piv = 0x7fffffff;
#pragma unroll
    for (int tv = 0; tv < 2; ++tv)
#pragma unroll
      for (int r = 0; r < 4; ++r) {
        float val = acc[tv][bt][r];
        int v = vbase + wave * 32 + tv * 16 + q * 4 + r;
        if (val > pmv) { pmv = val; piv = v; }  // strict >, v ascending in lane
      }
    lred[wave][q][bt * 16 + m] = pmv;
    lidx[wave][q][bt * 16 + m] = piv;
  }
  __syncthreads();
  if (tid < 64) {
    float bm = -INFINITY;
    int bi = 0x7fffffff;
#pragma unroll
    for (int w = 0; w < 4; ++w)
#pragma unroll
      for (int qq = 0; qq < 4; ++qq) {
        float v2 = lred[w][qq][tid];
        int i2 = lidx[w][qq][tid];
        if (v2 > bm || (v2 == bm && i2 < bi)) { bm = v2; bi = i2; }
      }
    bbm[tid] = bm;
    pmax_g[(size_t)tid * 256 + blk] = bm;
    pidx_g[(size_t)tid * 256 + blk] = bi;
  }
  __syncthreads();
#pragma unroll
  for (int bt = 0; bt < 4; ++bt) {
    float bm = bbm[bt * 16 + m];
    float s = 0.f;
#pragma unroll
    for (int tv = 0; tv < 2; ++tv)
#pragma unroll
      for (int r = 0; r < 4; ++r) s += expf(acc[tv][bt][r] - bm);
    lred[wave][q][bt * 16 + m] = s;
  }
  __syncthreads();
  if (tid < 64) {
    float s = 0.f;
#pragma unroll
    for (int w = 0; w < 4; ++w)
#pragma unroll
      for (int qq = 0; qq < 4; ++qq) s += lred[w][qq][tid];
    psum_g[(size_t)tid * 256 + blk] = s;
  }
}

// ----------------------------------------------- finalize: reduce partials --
// grid 64 (one block per b): global max/argmax/sum from 250 partials, mask,
// and x_next = E[argmax] gather.
__global__ __launch_bounds__(256) void finalize_kernel(
    const float* __restrict__ pm, const float* __restrict__ ps,
    const int* __restrict__ pig, const float* __restrict__ out_t,
    const float* __restrict__ E, float* __restrict__ x,
    float* __restrict__ mask) {
  __shared__ float sm[256];
  __shared__ int si[256];
  __shared__ float ss[256];
  const int b = blockIdx.x, tid = threadIdx.x;
  float m = -INFINITY;
  int idx = 0x7fffffff;
  if (tid < 250) {
    m = pm[(size_t)b * 256 + tid];
    idx = pig[(size_t)b * 256 + tid];
  }
  sm[tid] = m;
  si[tid] = idx;
  __syncthreads();
  for (int off = 128; off > 0; off >>= 1) {
    if (tid < off) {
      float o = sm[tid + off];
      int oi = si[tid + off];
      if (o > sm[tid] || (o == sm[tid] && oi < si[tid])) {
        sm[tid] = o;
        si[tid] = oi;
      }
    }
    __syncthreads();
  }
  const float M = sm[0];
  const int amax = si[0];
  float term = 0.f;
  if (tid < 250) term = ps[(size_t)b * 256 + tid] * expf(m - M);
  ss[tid] = term;
  __syncthreads();
  for (int off = 128; off > 0; off >>= 1) {
    if (tid < off) ss[tid] += ss[tid + off];
    __syncthreads();
  }
  if (tid == 0) mask[b] = expf(out_t[(size_t)b * kV + kEOS] - M) / ss[0];
  for (int u = tid; u < kH; u += 256)
    x[(size_t)u * 64 + b] = E[(size_t)amax * kH + u];
}

// -------------------------------------------------------------- launch ------
extern "C" void kernel_launch(void* const* d_in, const int* in_sizes, int n_in,
                              void* d_out, int out_size, void* d_ws,
                              size_t ws_size, hipStream_t stream) {
  const float* E = (const float*)d_in[0];
  const float* Wih = (const float*)d_in[1];
  const float* Whh = (const float*)d_in[2];
  const float* bih = (const float*)d_in[3];
  const float* bhh = (const float*)d_in[4];
  const float* Wout = (const float*)d_in[5];
  const float* bout = (const float*)d_in[6];
  const float* eh = (const float*)d_in[7];
  const float* ec = (const float*)d_in[8];
  float* out = (float*)d_out;
  float* ws = (float*)d_ws;

  float* x = ws;
  float* h = ws + 65536;
  float* c = ws + 131072;
  float* part = ws + 196608;
  float* pmaxg = ws + 2293760;
  float* psumg = ws + 2310144;
  int* pidxg = (int*)(ws + 2326528);
  unsigned short* Whi = (unsigned short*)(ws + 2359296);
  unsigned short* Wlo = Whi + (size_t)kV * kH;
  unsigned short* Hhi = Wlo + (size_t)kV * kH;
  unsigned short* Hlo = Hhi + (size_t)kB * kH;

  init_kernel<<<256, 256, 0, stream>>>(E, eh, ec, ws);
  wsplit_kernel<<<kV, 256, 0, stream>>>(Wout, Whi, Wlo);  // 32000 blocks
  for (int t = 0; t < kT; ++t) {
    float* out_t = out + (size_t)t * kB * kV;
    gates_kernel<<<dim3(64, 8), 256, 0, stream>>>(Wih, Whh, x, h, part);
    lstm_kernel<<<256, 256, 0, stream>>>(part, bih, bhh, h, c, Hhi, Hlo);
    logits_mfma_kernel<<<250, 256, 0, stream>>>(Whi, Wlo, Hhi, Hlo, bout,
                                                out_t, pmaxg, psumg, pidxg);
    finalize_kernel<<<64, 256, 0, stream>>>(pmaxg, psumg, pidxg, out_t, E, x,
                                            out + (size_t)kT * kB * kV + t * kB);
  }
}